// Round 2
// baseline (536.287 us; speedup 1.0000x reference)
//
#include <hip/hip_runtime.h>
#include <math.h>

#define D_MODEL 768
#define EMB 33
#define ORDER 64
#define SEQ 8192
#define BATCH 2
#define M 8192      // half-size complex FFT length (N = 16384 real)
#define LOGM 13

#define PI_F 3.14159265358979323846f

__device__ __forceinline__ int rev13(int x) { return (int)(__brev((unsigned)x) >> 19); }

// ---------------- MLP: h3[l][64] = sin-MLP(z[l]) ----------------
__global__ __launch_bounds__(256) void mlp_kernel(
    const float* __restrict__ z, const float* __restrict__ freq,
    const float* __restrict__ W1, const float* __restrict__ b1,
    const float* __restrict__ W2, const float* __restrict__ b2,
    const float* __restrict__ W3, const float* __restrict__ b3,
    float* __restrict__ h3out)
{
    __shared__ float sW1[ORDER * EMB];
    __shared__ float sW2[ORDER * ORDER];
    __shared__ float sW3[ORDER * ORDER];
    __shared__ float sb1[ORDER], sb2[ORDER], sb3[ORDER], sfr[ORDER];
    int t = threadIdx.x;
    for (int i = t; i < ORDER * EMB; i += 256) sW1[i] = W1[i];
    for (int i = t; i < ORDER * ORDER; i += 256) { sW2[i] = W2[i]; sW3[i] = W3[i]; }
    if (t < ORDER) { sb1[t] = b1[t]; sb2[t] = b2[t]; sb3[t] = b3[t]; sfr[t] = freq[t]; }
    __syncthreads();

    int l = blockIdx.x * 256 + t;
    float zv[EMB];
#pragma unroll
    for (int e = 0; e < EMB; e++) zv[e] = z[(size_t)l * EMB + e];

    float a[ORDER];
#pragma unroll
    for (int o = 0; o < ORDER; o++) {
        float acc = sb1[o];
#pragma unroll
        for (int e = 0; e < EMB; e++) acc = fmaf(zv[e], sW1[o * EMB + e], acc);
        a[o] = __sinf(sfr[o] * acc);
    }
    float bb[ORDER];
#pragma unroll
    for (int o = 0; o < ORDER; o++) {
        float acc = sb2[o];
#pragma unroll
        for (int q = 0; q < ORDER; q++) acc = fmaf(a[q], sW2[o * ORDER + q], acc);
        bb[o] = __sinf(sfr[o] * acc);
    }
#pragma unroll
    for (int o = 0; o < ORDER; o++) {
        float acc = sb3[o];
#pragma unroll
        for (int q = 0; q < ORDER; q++) acc = fmaf(bb[q], sW3[o * ORDER + q], acc);
        a[o] = __sinf(sfr[o] * acc);
    }
    float4* hp = (float4*)(h3out + (size_t)l * ORDER);
#pragma unroll
    for (int o = 0; o < ORDER; o += 4)
        hp[o >> 2] = make_float4(a[o], a[o + 1], a[o + 2], a[o + 3]);
}

// ---------------- filter: k[d][l] = (h3[l]·Wout[d]) * exp(-t[l]*|delta[d]|) ----------------
__global__ __launch_bounds__(256) void filt_kernel(
    const float* __restrict__ h3, const float* __restrict__ Wout,
    const float* __restrict__ tvec, const float* __restrict__ deltas,
    float* __restrict__ kout)
{
    __shared__ float hs[64][65];
    __shared__ float wsm[64][65];
    int t = threadIdx.x;
    int l0 = blockIdx.x * 64, d0 = blockIdx.y * 64;
    for (int m = t; m < 4096; m += 256) {
        int r = m >> 6, c = m & 63;
        hs[r][c] = h3[(size_t)(l0 + r) * 64 + c];
        wsm[r][c] = Wout[(size_t)(d0 + r) * 64 + c];
    }
    __syncthreads();
    int tx = t & 63, ty = t >> 6;
    float acc[16];
#pragma unroll
    for (int i = 0; i < 16; i++) acc[i] = 0.f;
#pragma unroll
    for (int kk = 0; kk < 64; kk++) {
        float hv = hs[tx][kk];
#pragma unroll
        for (int i = 0; i < 16; i++) acc[i] = fmaf(hv, wsm[ty * 16 + i][kk], acc[i]);
    }
    float tl = tvec[l0 + tx];
#pragma unroll
    for (int i = 0; i < 16; i++) {
        int d = d0 + ty * 16 + i;
        float kv = acc[i] * __expf(-tl * fabsf(deltas[d]));
        kout[(size_t)d * SEQ + l0 + tx] = kv;
    }
}

// ---------------- in-LDS radix-2 FFTs (M = 8192, 512 threads) ----------------
__device__ __forceinline__ void fft_dif_8192(float* re, float* im, int t)
{
    // natural input -> bit-reversed output, twiddles exp(-i...)
    for (int s = 0; s < LOGM; ++s) {
        int half = (M / 2) >> s;
        float ang_scale = -PI_F / (float)half;
        if (half <= 512) {
            // j identical for all 8 butterflies of this thread
            int j = t & (half - 1);
            float sn, cs;
            __sincosf(ang_scale * (float)j, &sn, &cs);
            for (int bf = t; bf < M / 2; bf += 512) {
                int i0 = ((bf ^ j) << 1) | j;
                int i1 = i0 + half;
                float ar = re[i0], ai = im[i0];
                float br = re[i1], bi = im[i1];
                re[i0] = ar + br; im[i0] = ai + bi;
                float dr = ar - br, di = ai - bi;
                re[i1] = dr * cs - di * sn;
                im[i1] = dr * sn + di * cs;
            }
        } else {
            for (int bf = t; bf < M / 2; bf += 512) {
                int j = bf & (half - 1);
                int i0 = ((bf ^ j) << 1) | j;
                int i1 = i0 + half;
                float ar = re[i0], ai = im[i0];
                float br = re[i1], bi = im[i1];
                float sn, cs;
                __sincosf(ang_scale * (float)j, &sn, &cs);
                re[i0] = ar + br; im[i0] = ai + bi;
                float dr = ar - br, di = ai - bi;
                re[i1] = dr * cs - di * sn;
                im[i1] = dr * sn + di * cs;
            }
        }
        __syncthreads();
    }
}

__device__ __forceinline__ void fft_dit_inv_8192(float* re, float* im, int t)
{
    // bit-reversed input -> natural output, twiddles exp(+i...), unnormalized
    for (int s = 0; s < LOGM; ++s) {
        int half = 1 << s;
        float ang_scale = PI_F / (float)half;
        if (half <= 512) {
            int j = t & (half - 1);
            float sn, cs;
            __sincosf(ang_scale * (float)j, &sn, &cs);
            for (int bf = t; bf < M / 2; bf += 512) {
                int i0 = ((bf ^ j) << 1) | j;
                int i1 = i0 + half;
                float ar = re[i0], ai = im[i0];
                float br = re[i1], bi = im[i1];
                float tr = br * cs - bi * sn;
                float ti = br * sn + bi * cs;
                re[i0] = ar + tr; im[i0] = ai + ti;
                re[i1] = ar - tr; im[i1] = ai - ti;
            }
        } else {
            for (int bf = t; bf < M / 2; bf += 512) {
                int j = bf & (half - 1);
                int i0 = ((bf ^ j) << 1) | j;
                int i1 = i0 + half;
                float ar = re[i0], ai = im[i0];
                float br = re[i1], bi = im[i1];
                float sn, cs;
                __sincosf(ang_scale * (float)j, &sn, &cs);
                float tr = br * cs - bi * sn;
                float ti = br * sn + bi * cs;
                re[i0] = ar + tr; im[i0] = ai + ti;
                re[i1] = ar - tr; im[i1] = ai - ti;
            }
        }
        __syncthreads();
    }
}

// ---------------- fused per-d: K_f = rfft(k_d) in LDS; then conv both batches ----------------
// outk: d_out. Row (0,d) holds k_d on entry (written by filt_kernel); this block
// consumes it before overwriting with y(0,d). 131080 B LDS -> 1 block/CU.
__global__ __launch_bounds__(512) void kfconv_kernel(
    const float* __restrict__ x, const float* __restrict__ bias,
    float* outk)
{
    __shared__ float Are[M], Aim[M];
    __shared__ float Bre[M + 1], Bim[M + 1];
    int t = threadIdx.x, d = blockIdx.x;

    // ---- load k_d packed even/odd, zero-pad ----
    const float* kp = outk + (size_t)d * SEQ;
    for (int n = t; n < 4096; n += 512) {
        float2 v = ((const float2*)kp)[n];
        Are[n] = v.x; Aim[n] = v.y;
    }
    for (int n = 4096 + t; n < M; n += 512) { Are[n] = 0.f; Aim[n] = 0.f; }
    __syncthreads();
    fft_dif_8192(Are, Aim, t);

    // ---- extract K_f[0..8192] into B ----
    for (int j = t; j <= 4096; j += 512) {
        int jm = (M - j) & (M - 1);
        int p0 = rev13(j), p1 = rev13(jm);
        float z1r = Are[p0], z1i = Aim[p0];
        float z2r = Are[p1], z2i = Aim[p1];
        float Ar = 0.5f * (z1r + z2r), Ai = 0.5f * (z1i - z2i);
        float Br = 0.5f * (z1i + z2i), Bi = 0.5f * (z2r - z1r);
        float sn, cs;
        __sincosf(-PI_F * (float)j * (1.0f / 8192.0f), &sn, &cs);  // W_N^j, N=16384
        float wbr = cs * Br - sn * Bi, wbi = cs * Bi + sn * Br;
        Bre[j] = Ar + wbr;      Bim[j] = Ai + wbi;        // K[j]
        Bre[M - j] = Ar - wbr;  Bim[M - j] = -(Ai - wbi); // K[M-j] = conj(A - W^j B)
    }
    __syncthreads();

    const float invM = 1.0f / 8192.0f;
    float bd = bias[d];

    for (int b = 0; b < BATCH; ++b) {
        const float* xp = x + ((size_t)(b * D_MODEL + d)) * SEQ;
        for (int n = t; n < 4096; n += 512) {
            float2 v = ((const float2*)xp)[n];
            Are[n] = v.x; Aim[n] = v.y;
        }
        for (int n = 4096 + t; n < M; n += 512) { Are[n] = 0.f; Aim[n] = 0.f; }
        __syncthreads();
        fft_dif_8192(Are, Aim, t);

        // ---- spectral multiply + hermitian repack for half-size inverse ----
        for (int j = t; j <= 4096; j += 512) {
            int jm = (M - j) & (M - 1);
            int p0 = rev13(j), p1 = rev13(jm);
            float z1r = Are[p0], z1i = Aim[p0];
            float z2r = Are[p1], z2i = Aim[p1];
            float Ar = 0.5f * (z1r + z2r), Ai = 0.5f * (z1i - z2i);
            float Br = 0.5f * (z1i + z2i), Bi = 0.5f * (z2r - z1r);
            float sn, cs;
            __sincosf(-PI_F * (float)j * (1.0f / 8192.0f), &sn, &cs);
            float wbr = cs * Br - sn * Bi, wbi = cs * Bi + sn * Br;
            float U1r = Ar + wbr, U1i = Ai + wbi;          // U[j]
            float U2r = Ar - wbr, U2i = -(Ai - wbi);       // U[M-j]
            float K1r = Bre[j],     K1i = Bim[j];
            float K2r = Bre[M - j], K2i = Bim[M - j];
            float P1r = U1r * K1r - U1i * K1i, P1i = U1r * K1i + U1i * K1r;
            float P2r = U2r * K2r - U2i * K2i, P2i = U2r * K2i + U2i * K2r;
            float Er = 0.5f * (P1r + P2r), Ei = 0.5f * (P1i - P2i);
            float Or = 0.5f * (P1r - P2r), Oi = 0.5f * (P1i + P2i);
            float G = cs * Oi - sn * Or;
            float H = cs * Or + sn * Oi;
            Are[p0] = Er - G; Aim[p0] = Ei + H;                      // Q[j]
            if (j != 0) { Are[p1] = Er + G; Aim[p1] = -Ei + H; }     // Q[M-j]
        }
        __syncthreads();
        fft_dit_inv_8192(Are, Aim, t);

        float* op = outk + ((size_t)(b * D_MODEL + d)) * SEQ;
        for (int n = t; n < 4096; n += 512) {
            float2 xv = ((const float2*)xp)[n];
            float2 ov;
            ov.x = fmaf(Are[n], invM, xv.x * bd);
            ov.y = fmaf(Aim[n], invM, xv.y * bd);
            ((float2*)op)[n] = ov;
        }
        __syncthreads();  // A must be fully read before next batch reloads it
    }
}

extern "C" void kernel_launch(void* const* d_in, const int* in_sizes, int n_in,
                              void* d_out, int out_size, void* d_ws, size_t ws_size,
                              hipStream_t stream)
{
    (void)in_sizes; (void)n_in; (void)out_size; (void)d_ws; (void)ws_size;
    const float* x      = (const float*)d_in[0];
    // d_in[1] = L (always 8192, hardcoded)
    const float* z      = (const float*)d_in[2];
    const float* tvec   = (const float*)d_in[3];
    const float* freq   = (const float*)d_in[4];
    const float* W1     = (const float*)d_in[5];
    const float* b1     = (const float*)d_in[6];
    const float* W2     = (const float*)d_in[7];
    const float* b2     = (const float*)d_in[8];
    const float* W3     = (const float*)d_in[9];
    const float* b3     = (const float*)d_in[10];
    const float* Wout   = (const float*)d_in[11];
    const float* deltas = (const float*)d_in[12];
    const float* bias   = (const float*)d_in[13];
    float* out = (float*)d_out;

    // Zero-workspace plan: stage intermediates inside d_out (12,582,912 floats).
    //   k  -> out[0 .. 6291456)            (rows (b=0, d)); consumed by block d
    //                                       before that block overwrites row (0,d)
    //   h3 -> out[12058624 .. 12582912)    (tail of b=1 half); dead after filt_kernel
    float* h3 = out + (12582912 - 524288);
    float* k  = out;

    hipLaunchKernelGGL(mlp_kernel, dim3(SEQ / 256), dim3(256), 0, stream,
                       z, freq, W1, b1, W2, b2, W3, b3, h3);
    hipLaunchKernelGGL(filt_kernel, dim3(SEQ / 64, D_MODEL / 64), dim3(256), 0, stream,
                       h3, Wout, tvec, deltas, k);
    hipLaunchKernelGGL(kfconv_kernel, dim3(D_MODEL), dim3(512), 0, stream,
                       x, bias, out);
}

// Round 4
// 321.189 us; speedup vs baseline: 1.6697x; 1.6697x over previous
//
#include <hip/hip_runtime.h>
#include <hip/hip_fp16.h>
#include <math.h>

#define D_MODEL 768
#define EMB 33
#define ORDER 64
#define SEQ 8192
#define BATCH 2
#define M 8192      // half-size complex FFT length (N = 16384 real)

#define PI_F 3.14159265358979323846f

// padded LDS index: +9 per 128 elements (odd shift -> kills stride-128/16 bank patterns)
#define IDX(a) ((a) + ((a) >> 4) + ((a) >> 7))
#define LDS_SZ 8768

__device__ __forceinline__ int rev13(int x) { return (int)(__brev((unsigned)x) >> 19); }

// twiddle constants for register tail/head (angle pi*k/8)
__device__ __constant__ float C8[8] = {
    1.f, 0.9238795325f, 0.7071067812f, 0.3826834324f,
    0.f, -0.3826834324f, -0.7071067812f, -0.9238795325f };
__device__ __constant__ float S8n[8] = {   // -sin(pi k/8)  (forward DIF)
    0.f, -0.3826834324f, -0.7071067812f, -0.9238795325f,
    -1.f, -0.9238795325f, -0.7071067812f, -0.3826834324f };
__device__ __constant__ float S8p[8] = {   // +sin(pi k/8)  (inverse DIT)
    0.f, 0.3826834324f, 0.7071067812f, 0.9238795325f,
    1.f, 0.9238795325f, 0.7071067812f, 0.3826834324f };

// ---------------- MLP: h3[l][64] = sin-MLP(z[l]) (LDS-cooperative, no spills) ----
__global__ __launch_bounds__(256) void mlp_kernel(
    const float* __restrict__ z, const float* __restrict__ freq,
    const float* __restrict__ W1, const float* __restrict__ b1,
    const float* __restrict__ W2, const float* __restrict__ b2,
    const float* __restrict__ W3, const float* __restrict__ b3,
    float* __restrict__ h3out)
{
    __shared__ float sz[64 * 33];
    __shared__ float sW1[64 * 33];
    __shared__ float sW2[64 * 64];
    __shared__ float sW3[64 * 64];
    __shared__ float hA[64 * 65];
    __shared__ float hB[64 * 65];
    __shared__ float sb1[64], sb2[64], sb3[64], sfr[64];
    int t = threadIdx.x;
    int l0 = blockIdx.x * 64;
    for (int i = t; i < 2112; i += 256) { sz[i] = z[(size_t)l0 * 33 + i]; sW1[i] = W1[i]; }
    for (int i = t; i < 4096; i += 256) { sW2[i] = W2[i]; sW3[i] = W3[i]; }
    if (t < 64) { sb1[t] = b1[t]; sb2[t] = b2[t]; sb3[t] = b3[t]; sfr[t] = freq[t]; }
    __syncthreads();

    int l = t & 63, grp = t >> 6;
    float acc[16];
    // layer 1 (33 -> 64)
#pragma unroll
    for (int i = 0; i < 16; ++i) {
        int o = grp * 16 + i;
        float a = sb1[o];
        for (int e = 0; e < 33; ++e) a = fmaf(sz[l * 33 + e], sW1[o * 33 + e], a);
        acc[i] = __sinf(sfr[o] * a);
    }
#pragma unroll
    for (int i = 0; i < 16; ++i) hA[l * 65 + grp * 16 + i] = acc[i];
    __syncthreads();
    // layer 2
#pragma unroll
    for (int i = 0; i < 16; ++i) {
        int o = grp * 16 + i;
        float a = sb2[o];
        for (int q = 0; q < 64; ++q) a = fmaf(hA[l * 65 + q], sW2[o * 64 + q], a);
        acc[i] = __sinf(sfr[o] * a);
    }
#pragma unroll
    for (int i = 0; i < 16; ++i) hB[l * 65 + grp * 16 + i] = acc[i];
    __syncthreads();
    // layer 3
#pragma unroll
    for (int i = 0; i < 16; ++i) {
        int o = grp * 16 + i;
        float a = sb3[o];
        for (int q = 0; q < 64; ++q) a = fmaf(hB[l * 65 + q], sW3[o * 64 + q], a);
        acc[i] = __sinf(sfr[o] * a);
    }
#pragma unroll
    for (int i = 0; i < 16; ++i) hA[l * 65 + grp * 16 + i] = acc[i];
    __syncthreads();
    for (int i = t; i < 4096; i += 256) {
        int ll = i >> 6, o = i & 63;
        h3out[(size_t)l0 * 64 + i] = hA[ll * 65 + o];
    }
}

// ---------------- filter: k[d][l] = (h3[l]·Wout[d]) * exp(-t[l]*|delta[d]|) ------
__global__ __launch_bounds__(256) void filt_kernel(
    const float* __restrict__ h3, const float* __restrict__ Wout,
    const float* __restrict__ tvec, const float* __restrict__ deltas,
    float* __restrict__ kout)
{
    __shared__ float hs[64][65];
    __shared__ float wsm[64][65];
    int t = threadIdx.x;
    int l0 = blockIdx.x * 64, d0 = blockIdx.y * 64;
    for (int m = t; m < 4096; m += 256) {
        int r = m >> 6, c = m & 63;
        hs[r][c] = h3[(size_t)(l0 + r) * 64 + c];
        wsm[r][c] = Wout[(size_t)(d0 + r) * 64 + c];
    }
    __syncthreads();
    int tx = t & 63, ty = t >> 6;
    float acc[16];
#pragma unroll
    for (int i = 0; i < 16; i++) acc[i] = 0.f;
#pragma unroll
    for (int kk = 0; kk < 64; kk++) {
        float hv = hs[tx][kk];
#pragma unroll
        for (int i = 0; i < 16; i++) acc[i] = fmaf(hv, wsm[ty * 16 + i][kk], acc[i]);
    }
    float tl = tvec[l0 + tx];
#pragma unroll
    for (int i = 0; i < 16; i++) {
        int d = d0 + ty * 16 + i;
        float kv = acc[i] * __expf(-tl * fabsf(deltas[d]));
        kout[(size_t)d * SEQ + l0 + tx] = kv;
    }
}

// ---------------- forward FFT (M=8192, 512 thr): fused radix-2 pairs ------------
__device__ __forceinline__ void fft_fwd(float* Ar, float* Ai, int t)
{
    // fused double stages: (4096,2048) (1024,512) (256,128) (64,32)
#pragma unroll
    for (int s = 0; s < 4; ++s) {
        const int h = 4096 >> (2 * s);
        const int h2 = h >> 1;
        const float ang = -PI_F / (float)h;
#pragma unroll
        for (int m = 0; m < 4; ++m) {
            int g = t + (m << 9);
            int j = g & (h2 - 1);
            int i = ((g - j) << 2) | j;          // block*2h + j
            int a0 = IDX(i), a1 = IDX(i + h2), a2 = IDX(i + h), a3 = IDX(i + h + h2);
            float sn, cs;
            __sincosf(ang * (float)j, &sn, &cs);
            float e0r = Ar[a0], e0i = Ai[a0];
            float e1r = Ar[a1], e1i = Ai[a1];
            float e2r = Ar[a2], e2i = Ai[a2];
            float e3r = Ar[a3], e3i = Ai[a3];
            float u0r = e0r + e2r, u0i = e0i + e2i;
            float d0r = e0r - e2r, d0i = e0i - e2i;
            float v0r = d0r * cs - d0i * sn, v0i = d0r * sn + d0i * cs;   // *W
            float u1r = e1r + e3r, u1i = e1i + e3i;
            float d1r = e1r - e3r, d1i = e1i - e3i;
            float v1r = d1r * sn + d1i * cs, v1i = d1i * sn - d1r * cs;   // *W*(-i)
            float c2 = cs * cs - sn * sn, s2 = 2.f * sn * cs;             // W^2
            Ar[a0] = u0r + u1r; Ai[a0] = u0i + u1i;
            float pr = u0r - u1r, pi = u0i - u1i;
            Ar[a1] = pr * c2 - pi * s2; Ai[a1] = pr * s2 + pi * c2;
            Ar[a2] = v0r + v1r; Ai[a2] = v0i + v1i;
            float rr = v0r - v1r, ri = v0i - v1i;
            Ar[a3] = rr * c2 - ri * s2; Ai[a3] = rr * s2 + ri * c2;
        }
        __syncthreads();
    }
    // single radix-2 stage h=16 (one sincos per thread)
    {
        const int j = t & 15;
        float sn, cs;
        __sincosf((-PI_F / 16.f) * (float)j, &sn, &cs);
#pragma unroll
        for (int m = 0; m < 8; ++m) {
            int bf = t + (m << 9);
            int i0 = ((bf >> 4) << 5) | j;
            int a0 = IDX(i0), a1 = IDX(i0 + 16);
            float arr = Ar[a0], aii = Ai[a0];
            float brr = Ar[a1], bii = Ai[a1];
            Ar[a0] = arr + brr; Ai[a0] = aii + bii;
            float dr = arr - brr, di = aii - bii;
            Ar[a1] = dr * cs - di * sn; Ai[a1] = dr * sn + di * cs;
        }
        __syncthreads();
    }
    // register tail: h = 8,4,2,1 on 16 consecutive elements per thread
    {
        int pb = IDX(16 * t);   // 16 consecutive elements, no pad-boundary crossing
        float fr[16], fi[16];
#pragma unroll
        for (int e = 0; e < 16; ++e) { fr[e] = Ar[pb + e]; fi[e] = Ai[pb + e]; }
#pragma unroll
        for (int k = 0; k < 8; ++k) {                     // h=8
            float cs = C8[k], sn = S8n[k];
            float arr = fr[k], aii = fi[k], brr = fr[k + 8], bii = fi[k + 8];
            fr[k] = arr + brr; fi[k] = aii + bii;
            float dr = arr - brr, di = aii - bii;
            fr[k + 8] = dr * cs - di * sn; fi[k + 8] = dr * sn + di * cs;
        }
#pragma unroll
        for (int b0 = 0; b0 < 16; b0 += 8)                // h=4
#pragma unroll
            for (int k = 0; k < 4; ++k) {
                float cs = C8[2 * k], sn = S8n[2 * k];
                int i0 = b0 + k, i1 = i0 + 4;
                float arr = fr[i0], aii = fi[i0], brr = fr[i1], bii = fi[i1];
                fr[i0] = arr + brr; fi[i0] = aii + bii;
                float dr = arr - brr, di = aii - bii;
                fr[i1] = dr * cs - di * sn; fi[i1] = dr * sn + di * cs;
            }
#pragma unroll
        for (int b0 = 0; b0 < 16; b0 += 4)                // h=2
#pragma unroll
            for (int k = 0; k < 2; ++k) {
                float cs = C8[4 * k], sn = S8n[4 * k];
                int i0 = b0 + k, i1 = i0 + 2;
                float arr = fr[i0], aii = fi[i0], brr = fr[i1], bii = fi[i1];
                fr[i0] = arr + brr; fi[i0] = aii + bii;
                float dr = arr - brr, di = aii - bii;
                fr[i1] = dr * cs - di * sn; fi[i1] = dr * sn + di * cs;
            }
#pragma unroll
        for (int b0 = 0; b0 < 16; b0 += 2) {              // h=1
            float arr = fr[b0], aii = fi[b0], brr = fr[b0 + 1], bii = fi[b0 + 1];
            fr[b0] = arr + brr; fi[b0] = aii + bii;
            fr[b0 + 1] = arr - brr; fi[b0 + 1] = aii - bii;
        }
#pragma unroll
        for (int e = 0; e < 16; ++e) { Ar[pb + e] = fr[e]; Ai[pb + e] = fi[e]; }
        __syncthreads();
    }
}

// ---------------- inverse FFT (bit-reversed in, natural out, unnormalized) ------
__device__ __forceinline__ void fft_inv(float* Ar, float* Ai, int t)
{
    // register head: h = 1,2,4,8
    {
        int pb = IDX(16 * t);
        float fr[16], fi[16];
#pragma unroll
        for (int e = 0; e < 16; ++e) { fr[e] = Ar[pb + e]; fi[e] = Ai[pb + e]; }
#pragma unroll
        for (int b0 = 0; b0 < 16; b0 += 2) {              // h=1
            float arr = fr[b0], aii = fi[b0], brr = fr[b0 + 1], bii = fi[b0 + 1];
            fr[b0] = arr + brr; fi[b0] = aii + bii;
            fr[b0 + 1] = arr - brr; fi[b0 + 1] = aii - bii;
        }
#pragma unroll
        for (int b0 = 0; b0 < 16; b0 += 4)                // h=2
#pragma unroll
            for (int k = 0; k < 2; ++k) {
                float cs = C8[4 * k], sn = S8p[4 * k];
                int i0 = b0 + k, i1 = i0 + 2;
                float arr = fr[i0], aii = fi[i0], brr = fr[i1], bii = fi[i1];
                float tr = brr * cs - bii * sn, ti = brr * sn + bii * cs;
                fr[i0] = arr + tr; fi[i0] = aii + ti;
                fr[i1] = arr - tr; fi[i1] = aii - ti;
            }
#pragma unroll
        for (int b0 = 0; b0 < 16; b0 += 8)                // h=4
#pragma unroll
            for (int k = 0; k < 4; ++k) {
                float cs = C8[2 * k], sn = S8p[2 * k];
                int i0 = b0 + k, i1 = i0 + 4;
                float arr = fr[i0], aii = fi[i0], brr = fr[i1], bii = fi[i1];
                float tr = brr * cs - bii * sn, ti = brr * sn + bii * cs;
                fr[i0] = arr + tr; fi[i0] = aii + ti;
                fr[i1] = arr - tr; fi[i1] = aii - ti;
            }
#pragma unroll
        for (int k = 0; k < 8; ++k) {                     // h=8
            float cs = C8[k], sn = S8p[k];
            float arr = fr[k], aii = fi[k], brr = fr[k + 8], bii = fi[k + 8];
            float tr = brr * cs - bii * sn, ti = brr * sn + bii * cs;
            fr[k] = arr + tr; fi[k] = aii + ti;
            fr[k + 8] = arr - tr; fi[k + 8] = aii - ti;
        }
#pragma unroll
        for (int e = 0; e < 16; ++e) { Ar[pb + e] = fr[e]; Ai[pb + e] = fi[e]; }
        __syncthreads();
    }
    // single h=16 (DIT)
    {
        const int j = t & 15;
        float sn, cs;
        __sincosf((PI_F / 16.f) * (float)j, &sn, &cs);
#pragma unroll
        for (int m = 0; m < 8; ++m) {
            int bf = t + (m << 9);
            int i0 = ((bf >> 4) << 5) | j;
            int a0 = IDX(i0), a1 = IDX(i0 + 16);
            float arr = Ar[a0], aii = Ai[a0];
            float brr = Ar[a1], bii = Ai[a1];
            float tr = brr * cs - bii * sn, ti = brr * sn + bii * cs;
            Ar[a0] = arr + tr; Ai[a0] = aii + ti;
            Ar[a1] = arr - tr; Ai[a1] = aii - ti;
        }
        __syncthreads();
    }
    // fused double stages: (32,64) (128,256) (512,1024) (2048,4096)
#pragma unroll
    for (int s = 0; s < 4; ++s) {
        const int q = 32 << (2 * s);
        const float ang = PI_F / (float)(2 * q);
#pragma unroll
        for (int m = 0; m < 4; ++m) {
            int g = t + (m << 9);
            int j = g & (q - 1);
            int i = ((g - j) << 2) | j;          // block*4q + j
            int a0 = IDX(i), a1 = IDX(i + q), a2 = IDX(i + 2 * q), a3 = IDX(i + 3 * q);
            float sb, cb;
            __sincosf(ang * (float)j, &sb, &cb);
            float ca = cb * cb - sb * sb, sa = 2.f * sb * cb;   // double angle
            float e0r = Ar[a0], e0i = Ai[a0];
            float e1r = Ar[a1], e1i = Ai[a1];
            float e2r = Ar[a2], e2i = Ai[a2];
            float e3r = Ar[a3], e3i = Ai[a3];
            float t1r = e1r * ca - e1i * sa, t1i = e1r * sa + e1i * ca;
            float u0r = e0r + t1r, u0i = e0i + t1i;
            float u1r = e0r - t1r, u1i = e0i - t1i;
            float t3r = e3r * ca - e3i * sa, t3i = e3r * sa + e3i * ca;
            float u2r = e2r + t3r, u2i = e2i + t3i;
            float u3r = e2r - t3r, u3i = e2i - t3i;
            float t2r = u2r * cb - u2i * sb, t2i = u2r * sb + u2i * cb;
            Ar[a0] = u0r + t2r; Ai[a0] = u0i + t2i;
            Ar[a2] = u0r - t2r; Ai[a2] = u0i - t2i;
            float t4r = -(u3r * sb + u3i * cb), t4i = u3r * cb - u3i * sb;  // *i*Wb
            Ar[a1] = u1r + t4r; Ai[a1] = u1i + t4i;
            Ar[a3] = u1r - t4r; Ai[a3] = u1i - t4i;
        }
        __syncthreads();
    }
}

// ---------------- kf: K_f[d] = rfft(k_d, 16384), fp16-packed into d_out rows ----
// P[j] (half2): j=0 -> (K[0].re, K[8192].re); else (K[j].re, K[j].im).
// Written to BOTH row (0,d) and row (1,d) so conv grid is (d,b) race-free.
__global__ __launch_bounds__(512, 4) void kf_kernel(float* outk)
{
    __shared__ float Are[LDS_SZ], Aim[LDS_SZ];
    int t = threadIdx.x, d = blockIdx.x;
    const float* kp = outk + (size_t)d * SEQ;
    for (int n = t; n < 4096; n += 512) {
        float2 v = ((const float2*)kp)[n];
        Are[IDX(n)] = v.x; Aim[IDX(n)] = v.y;
    }
    for (int n = 4096 + t; n < M; n += 512) { Are[IDX(n)] = 0.f; Aim[IDX(n)] = 0.f; }
    __syncthreads();
    fft_fwd(Are, Aim, t);

    __half2* P0 = (__half2*)(outk + (size_t)d * SEQ);
    __half2* P1 = (__half2*)(outk + (size_t)(D_MODEL + d) * SEQ);
    for (int j = t; j <= 4096; j += 512) {
        int jm = (M - j) & (M - 1);
        int p0 = rev13(j), p1 = rev13(jm);
        float z1r = Are[IDX(p0)], z1i = Aim[IDX(p0)];
        float z2r = Are[IDX(p1)], z2i = Aim[IDX(p1)];
        float Ar_ = 0.5f * (z1r + z2r), Ai_ = 0.5f * (z1i - z2i);
        float Br_ = 0.5f * (z1i + z2i), Bi_ = 0.5f * (z2r - z1r);
        float sn, cs;
        __sincosf(-PI_F * (float)j * (1.0f / 8192.0f), &sn, &cs);  // W_16384^j
        float wbr = cs * Br_ - sn * Bi_, wbi = cs * Bi_ + sn * Br_;
        float K1r = Ar_ + wbr, K1i = Ai_ + wbi;          // K[j]
        float K2r = Ar_ - wbr, K2i = -(Ai_ - wbi);       // K[M-j]
        if (j == 0) {
            __half2 v = __floats2half2_rn(K1r, K2r);     // DC and Nyquist (both real)
            P0[0] = v; P1[0] = v;
        } else {
            __half2 v1 = __floats2half2_rn(K1r, K1i);
            P0[j] = v1; P1[j] = v1;
            if (j != 4096) {
                __half2 v2 = __floats2half2_rn(K2r, K2i);
                P0[M - j] = v2; P1[M - j] = v2;
            }
        }
    }
}

// ---------------- conv: block (d,b): y = irfft(rfft(x)*K)[:8192] + x*bias -------
__global__ __launch_bounds__(512, 4) void conv_kernel(
    const float* __restrict__ x, const float* __restrict__ bias,
    float* outk)
{
    __shared__ float Are[LDS_SZ], Aim[LDS_SZ];
    int t = threadIdx.x, d = blockIdx.x, b = blockIdx.y;
    const float* xp = x + ((size_t)(b * D_MODEL + d)) * SEQ;

    for (int n = t; n < 4096; n += 512) {
        float2 v = ((const float2*)xp)[n];
        Are[IDX(n)] = v.x; Aim[IDX(n)] = v.y;
    }
    for (int n = 4096 + t; n < M; n += 512) { Are[IDX(n)] = 0.f; Aim[IDX(n)] = 0.f; }
    __syncthreads();
    fft_fwd(Are, Aim, t);

    const __half2* P = (const __half2*)(outk + (size_t)(b * D_MODEL + d) * SEQ);
    for (int j = t; j <= 4096; j += 512) {
        int jm = (M - j) & (M - 1);
        int p0 = rev13(j), p1 = rev13(jm);
        int q0 = IDX(p0), q1 = IDX(p1);
        float z1r = Are[q0], z1i = Aim[q0];
        float z2r = Are[q1], z2i = Aim[q1];
        float Ar_ = 0.5f * (z1r + z2r), Ai_ = 0.5f * (z1i - z2i);
        float Br_ = 0.5f * (z1i + z2i), Bi_ = 0.5f * (z2r - z1r);
        float sn, cs;
        __sincosf(-PI_F * (float)j * (1.0f / 8192.0f), &sn, &cs);
        float wbr = cs * Br_ - sn * Bi_, wbi = cs * Bi_ + sn * Br_;
        float U1r = Ar_ + wbr, U1i = Ai_ + wbi;          // U[j]
        float U2r = Ar_ - wbr, U2i = -(Ai_ - wbi);       // U[M-j]
        float K1r, K1i, K2r, K2i;
        if (j == 0) {
            __half2 v = P[0];
            K1r = __low2float(v);  K1i = 0.f;
            K2r = __high2float(v); K2i = 0.f;
        } else {
            __half2 v1 = P[j];
            __half2 v2 = P[M - j];
            K1r = __low2float(v1); K1i = __high2float(v1);
            K2r = __low2float(v2); K2i = __high2float(v2);
        }
        float P1r = U1r * K1r - U1i * K1i, P1i = U1r * K1i + U1i * K1r;
        float P2r = U2r * K2r - U2i * K2i, P2i = U2r * K2i + U2i * K2r;
        float Er = 0.5f * (P1r + P2r), Ei = 0.5f * (P1i - P2i);
        float Or = 0.5f * (P1r - P2r), Oi = 0.5f * (P1i + P2i);
        float G = cs * Oi - sn * Or;
        float H = cs * Or + sn * Oi;
        Are[q0] = Er - G; Aim[q0] = Ei + H;                      // Q[j]
        if (j != 0) { Are[q1] = Er + G; Aim[q1] = -Ei + H; }     // Q[M-j]
    }
    __syncthreads();
    fft_inv(Are, Aim, t);

    const float invM = 1.0f / 8192.0f;
    float bd = bias[d];
    float* op = outk + ((size_t)(b * D_MODEL + d)) * SEQ;
    for (int n = t; n < 4096; n += 512) {
        float2 xv = ((const float2*)xp)[n];
        float2 ov;
        ov.x = fmaf(Are[IDX(n)], invM, xv.x * bd);
        ov.y = fmaf(Aim[IDX(n)], invM, xv.y * bd);
        ((float2*)op)[n] = ov;
    }
}

extern "C" void kernel_launch(void* const* d_in, const int* in_sizes, int n_in,
                              void* d_out, int out_size, void* d_ws, size_t ws_size,
                              hipStream_t stream)
{
    (void)in_sizes; (void)n_in; (void)out_size; (void)d_ws; (void)ws_size;
    const float* x      = (const float*)d_in[0];
    // d_in[1] = L (always 8192, hardcoded)
    const float* z      = (const float*)d_in[2];
    const float* tvec   = (const float*)d_in[3];
    const float* freq   = (const float*)d_in[4];
    const float* W1     = (const float*)d_in[5];
    const float* b1     = (const float*)d_in[6];
    const float* W2     = (const float*)d_in[7];
    const float* b2     = (const float*)d_in[8];
    const float* W3     = (const float*)d_in[9];
    const float* b3     = (const float*)d_in[10];
    const float* Wout   = (const float*)d_in[11];
    const float* deltas = (const float*)d_in[12];
    const float* bias   = (const float*)d_in[13];
    float* out = (float*)d_out;

    // staging inside d_out (12,582,912 floats):
    //   h3 -> last 64 rows of b=1 half (dead after filt_kernel)
    //   k  -> rows (0,d)   (consumed by kf block d, overwritten with packed K)
    //   K  -> rows (0,d) and (1,d) fp16-packed (consumed then overwritten by conv (d,b))
    float* h3 = out + ((size_t)(2 * D_MODEL - 64) * SEQ);
    float* k  = out;

    hipLaunchKernelGGL(mlp_kernel, dim3(SEQ / 64), dim3(256), 0, stream,
                       z, freq, W1, b1, W2, b2, W3, b3, h3);
    hipLaunchKernelGGL(filt_kernel, dim3(SEQ / 64, D_MODEL / 64), dim3(256), 0, stream,
                       h3, Wout, tvec, deltas, k);
    hipLaunchKernelGGL(kf_kernel, dim3(D_MODEL), dim3(512), 0, stream, out);
    hipLaunchKernelGGL(conv_kernel, dim3(D_MODEL, BATCH), dim3(512), 0, stream,
                       x, bias, out);
}

// Round 5
// 262.277 us; speedup vs baseline: 2.0447x; 1.2246x over previous
//
#include <hip/hip_runtime.h>
#include <hip/hip_fp16.h>
#include <math.h>

#define D_MODEL 768
#define EMB 33
#define ORDER 64
#define SEQ 8192
#define BATCH 2
#define M 8192      // half-size complex FFT length (N = 16384 real)

#define PI_F 3.14159265358979323846f

// padded LDS index: +1 per 16, +1 per 128 (odd shifts kill stride-16/128 bank patterns)
#define IDX(a) ((a) + ((a) >> 4) + ((a) >> 7))
#define LDS_SZ 8768

__device__ __forceinline__ int rev13(int x) { return (int)(__brev((unsigned)x) >> 19); }

// twiddle constants for register tail/head (angle pi*k/8)
__device__ __constant__ float C8[8] = {
    1.f, 0.9238795325f, 0.7071067812f, 0.3826834324f,
    0.f, -0.3826834324f, -0.7071067812f, -0.9238795325f };
__device__ __constant__ float S8n[8] = {   // -sin(pi k/8)  (forward DIF)
    0.f, -0.3826834324f, -0.7071067812f, -0.9238795325f,
    -1.f, -0.9238795325f, -0.7071067812f, -0.3826834324f };
__device__ __constant__ float S8p[8] = {   // +sin(pi k/8)  (inverse DIT)
    0.f, 0.3826834324f, 0.7071067812f, 0.9238795325f,
    1.f, 0.9238795325f, 0.7071067812f, 0.3826834324f };

// ---------------- MLP: h3[l][64] = sin-MLP(z[l]) (LDS-cooperative, no spills) ----
__global__ __launch_bounds__(256) void mlp_kernel(
    const float* __restrict__ z, const float* __restrict__ freq,
    const float* __restrict__ W1, const float* __restrict__ b1,
    const float* __restrict__ W2, const float* __restrict__ b2,
    const float* __restrict__ W3, const float* __restrict__ b3,
    float* __restrict__ h3out)
{
    __shared__ float sz[64 * 33];
    __shared__ float sW1[64 * 33];
    __shared__ float sW2[64 * 64];
    __shared__ float sW3[64 * 64];
    __shared__ float hA[64 * 65];
    __shared__ float hB[64 * 65];
    __shared__ float sb1[64], sb2[64], sb3[64], sfr[64];
    int t = threadIdx.x;
    int l0 = blockIdx.x * 64;
    for (int i = t; i < 2112; i += 256) { sz[i] = z[(size_t)l0 * 33 + i]; sW1[i] = W1[i]; }
    for (int i = t; i < 4096; i += 256) { sW2[i] = W2[i]; sW3[i] = W3[i]; }
    if (t < 64) { sb1[t] = b1[t]; sb2[t] = b2[t]; sb3[t] = b3[t]; sfr[t] = freq[t]; }
    __syncthreads();

    int l = t & 63, grp = t >> 6;
    float acc[16];
#pragma unroll
    for (int i = 0; i < 16; ++i) {
        int o = grp * 16 + i;
        float a = sb1[o];
        for (int e = 0; e < 33; ++e) a = fmaf(sz[l * 33 + e], sW1[o * 33 + e], a);
        acc[i] = __sinf(sfr[o] * a);
    }
#pragma unroll
    for (int i = 0; i < 16; ++i) hA[l * 65 + grp * 16 + i] = acc[i];
    __syncthreads();
#pragma unroll
    for (int i = 0; i < 16; ++i) {
        int o = grp * 16 + i;
        float a = sb2[o];
        for (int q = 0; q < 64; ++q) a = fmaf(hA[l * 65 + q], sW2[o * 64 + q], a);
        acc[i] = __sinf(sfr[o] * a);
    }
#pragma unroll
    for (int i = 0; i < 16; ++i) hB[l * 65 + grp * 16 + i] = acc[i];
    __syncthreads();
#pragma unroll
    for (int i = 0; i < 16; ++i) {
        int o = grp * 16 + i;
        float a = sb3[o];
        for (int q = 0; q < 64; ++q) a = fmaf(hB[l * 65 + q], sW3[o * 64 + q], a);
        acc[i] = __sinf(sfr[o] * a);
    }
#pragma unroll
    for (int i = 0; i < 16; ++i) hA[l * 65 + grp * 16 + i] = acc[i];
    __syncthreads();
    for (int i = t; i < 4096; i += 256) {
        int ll = i >> 6, o = i & 63;
        h3out[(size_t)l0 * 64 + i] = hA[ll * 65 + o];
    }
}

// ---------------- filter: k[d][l] = (h3[l]·Wout[d]) * exp(-t[l]*|delta[d]|) ------
__global__ __launch_bounds__(256) void filt_kernel(
    const float* __restrict__ h3, const float* __restrict__ Wout,
    const float* __restrict__ tvec, const float* __restrict__ deltas,
    float* __restrict__ kout)
{
    __shared__ float hs[64][65];
    __shared__ float wsm[64][65];
    int t = threadIdx.x;
    int l0 = blockIdx.x * 64, d0 = blockIdx.y * 64;
    for (int m = t; m < 4096; m += 256) {
        int r = m >> 6, c = m & 63;
        hs[r][c] = h3[(size_t)(l0 + r) * 64 + c];
        wsm[r][c] = Wout[(size_t)(d0 + r) * 64 + c];
    }
    __syncthreads();
    int tx = t & 63, ty = t >> 6;
    float acc[16];
#pragma unroll
    for (int i = 0; i < 16; i++) acc[i] = 0.f;
#pragma unroll
    for (int kk = 0; kk < 64; kk++) {
        float hv = hs[tx][kk];
#pragma unroll
        for (int i = 0; i < 16; i++) acc[i] = fmaf(hv, wsm[ty * 16 + i][kk], acc[i]);
    }
    float tl = tvec[l0 + tx];
#pragma unroll
    for (int i = 0; i < 16; i++) {
        int d = d0 + ty * 16 + i;
        float kv = acc[i] * __expf(-tl * fabsf(deltas[d]));
        kout[(size_t)d * SEQ + l0 + tx] = kv;
    }
}

// ---------------- radix-8 fused forward pass: stages (H, H/2, H/4) ---------------
template<int H>
__device__ __forceinline__ void fwd8(float* Ar, float* Ai, int t)
{
    constexpr int H4 = H / 4;
    int j0 = t & (H4 - 1);
    float c1, s1;
    __sincosf((-PI_F / (float)H) * (float)j0, &s1, &c1);
#pragma unroll
    for (int gg = 0; gg < 2; ++gg) {
        int g = t + (gg << 9);
        int j = g & (H4 - 1);
        int i = ((g & ~(H4 - 1)) << 3) | j;
        float c1g = c1, s1g = s1;
        if (H4 > 512 && gg == 1) {       // only H=4096: j differs by 512 -> rotate T1
            const float cR = 0.9238795325f, sR = -0.3826834324f;  // exp(-i*pi/8)
            c1g = c1 * cR - s1 * sR;
            s1g = s1 * cR + c1 * sR;
        }
        float c2 = c1g * c1g - s1g * s1g, s2 = 2.f * c1g * s1g;   // T1^2
        float c3 = c2 * c2 - s2 * s2,     s3 = 2.f * c2 * s2;     // T1^4
        float xr[8], xi[8];
        int ad[8];
#pragma unroll
        for (int m = 0; m < 8; ++m) { ad[m] = IDX(i + m * H4); xr[m] = Ar[ad[m]]; xi[m] = Ai[ad[m]]; }
        const float r = 0.70710678118f;
        float twc[4], tws[4];                                      // T1 * W8^m
        twc[0] = c1g;             tws[0] = s1g;
        twc[1] = r * (c1g + s1g); tws[1] = r * (s1g - c1g);
        twc[2] = s1g;             tws[2] = -c1g;
        twc[3] = r * (s1g - c1g); tws[3] = -r * (c1g + s1g);
#pragma unroll
        for (int m = 0; m < 4; ++m) {                              // stage half=H
            float ur = xr[m] + xr[m + 4], ui = xi[m] + xi[m + 4];
            float dr = xr[m] - xr[m + 4], di = xi[m] - xi[m + 4];
            xr[m] = ur; xi[m] = ui;
            xr[m + 4] = dr * twc[m] - di * tws[m];
            xi[m + 4] = dr * tws[m] + di * twc[m];
        }
#pragma unroll
        for (int base = 0; base < 8; base += 4)                    // stage half=H/2
#pragma unroll
            for (int mm = 0; mm < 2; ++mm) {
                int a = base + mm, b = a + 2;
                float ur = xr[a] + xr[b], ui = xi[a] + xi[b];
                float dr = xr[a] - xr[b], di = xi[a] - xi[b];
                xr[a] = ur; xi[a] = ui;
                if (mm == 0) { xr[b] = dr * c2 - di * s2; xi[b] = dr * s2 + di * c2; }
                else         { xr[b] = dr * s2 + di * c2; xi[b] = di * s2 - dr * c2; }  // *T2*(-i)
            }
#pragma unroll
        for (int m = 0; m < 8; m += 2) {                           // stage half=H/4
            float ur = xr[m] + xr[m + 1], ui = xi[m] + xi[m + 1];
            float dr = xr[m] - xr[m + 1], di = xi[m] - xi[m + 1];
            xr[m] = ur; xi[m] = ui;
            xr[m + 1] = dr * c3 - di * s3; xi[m + 1] = dr * s3 + di * c3;
        }
#pragma unroll
        for (int m = 0; m < 8; ++m) { Ar[ad[m]] = xr[m]; Ai[ad[m]] = xi[m]; }
    }
}

// ---------------- radix-8 fused inverse pass: stages (H, 2H, 4H) -----------------
template<int H>
__device__ __forceinline__ void inv8(float* Ar, float* Ai, int t)
{
    int j0 = t & (H - 1);
    float ct, st;
    __sincosf((PI_F / (float)(4 * H)) * (float)j0, &st, &ct);      // T = exp(i pi j/(4H))
#pragma unroll
    for (int gg = 0; gg < 2; ++gg) {
        int g = t + (gg << 9);
        int j = g & (H - 1);
        int i = ((g & ~(H - 1)) << 3) | j;
        float c = ct, s = st;
        if (H > 512 && gg == 1) {        // only H=1024: j differs by 512 -> rotate T
            const float cR = 0.9238795325f, sR = 0.3826834324f;    // exp(+i*pi/8)
            c = ct * cR - st * sR;
            s = st * cR + ct * sR;
        }
        float c2 = c * c - s * s, s2 = 2.f * c * s;                // T^2
        float c4 = c2 * c2 - s2 * s2, s4 = 2.f * c2 * s2;          // T^4
        float xr[8], xi[8]; int ad[8];
#pragma unroll
        for (int m = 0; m < 8; ++m) { ad[m] = IDX(i + m * H); xr[m] = Ar[ad[m]]; xi[m] = Ai[ad[m]]; }
        // stage half=H: pairs (m, m+1), tw = T^4
#pragma unroll
        for (int m = 0; m < 8; m += 2) {
            float tr = xr[m + 1] * c4 - xi[m + 1] * s4;
            float ti = xr[m + 1] * s4 + xi[m + 1] * c4;
            xr[m + 1] = xr[m] - tr; xi[m + 1] = xi[m] - ti;
            xr[m]     = xr[m] + tr; xi[m]     = xi[m] + ti;
        }
        // stage half=2H: pairs (m, m+2), tw = T^2 (m even) or T^2 * i (m odd)
#pragma unroll
        for (int base = 0; base < 8; base += 4)
#pragma unroll
            for (int mm = 0; mm < 2; ++mm) {
                int a = base + mm, b = a + 2;
                float tr, ti;
                if (mm == 0) { tr = xr[b] * c2 - xi[b] * s2; ti = xr[b] * s2 + xi[b] * c2; }
                else         { tr = -(xr[b] * s2 + xi[b] * c2); ti = xr[b] * c2 - xi[b] * s2; }
                xr[b] = xr[a] - tr; xi[b] = xi[a] - ti;
                xr[a] = xr[a] + tr; xi[a] = xi[a] + ti;
            }
        // stage half=4H: pairs (m, m+4), tw = T * e^{i pi m/4}
        const float r = 0.70710678118f;
        float t3c[4], t3s[4];
        t3c[0] = c;           t3s[0] = s;
        t3c[1] = r * (c - s); t3s[1] = r * (c + s);
        t3c[2] = -s;          t3s[2] = c;
        t3c[3] = -r * (c + s); t3s[3] = r * (c - s);
#pragma unroll
        for (int m = 0; m < 4; ++m) {
            float tr = xr[m + 4] * t3c[m] - xi[m + 4] * t3s[m];
            float ti = xr[m + 4] * t3s[m] + xi[m + 4] * t3c[m];
            xr[m + 4] = xr[m] - tr; xi[m + 4] = xi[m] - ti;
            xr[m]     = xr[m] + tr; xi[m]     = xi[m] + ti;
        }
#pragma unroll
        for (int m = 0; m < 8; ++m) { Ar[ad[m]] = xr[m]; Ai[ad[m]] = xi[m]; }
    }
}

// ---------------- forward FFT: 3 radix-8 LDS passes + register tail --------------
__device__ __forceinline__ void fft_fwd(float* Ar, float* Ai, int t)
{
    fwd8<4096>(Ar, Ai, t); __syncthreads();   // 4096,2048,1024
    fwd8<512>(Ar, Ai, t);  __syncthreads();   // 512,256,128
    fwd8<64>(Ar, Ai, t);   __syncthreads();   // 64,32,16
    // register tail: h = 8,4,2,1 on 16 consecutive elements per thread
    {
        int pb = IDX(16 * t);
        float fr[16], fi[16];
#pragma unroll
        for (int e = 0; e < 16; ++e) { fr[e] = Ar[pb + e]; fi[e] = Ai[pb + e]; }
#pragma unroll
        for (int k = 0; k < 8; ++k) {
            float cs = C8[k], sn = S8n[k];
            float arr = fr[k], aii = fi[k], brr = fr[k + 8], bii = fi[k + 8];
            fr[k] = arr + brr; fi[k] = aii + bii;
            float dr = arr - brr, di = aii - bii;
            fr[k + 8] = dr * cs - di * sn; fi[k + 8] = dr * sn + di * cs;
        }
#pragma unroll
        for (int b0 = 0; b0 < 16; b0 += 8)
#pragma unroll
            for (int k = 0; k < 4; ++k) {
                float cs = C8[2 * k], sn = S8n[2 * k];
                int i0 = b0 + k, i1 = i0 + 4;
                float arr = fr[i0], aii = fi[i0], brr = fr[i1], bii = fi[i1];
                fr[i0] = arr + brr; fi[i0] = aii + bii;
                float dr = arr - brr, di = aii - bii;
                fr[i1] = dr * cs - di * sn; fi[i1] = dr * sn + di * cs;
            }
#pragma unroll
        for (int b0 = 0; b0 < 16; b0 += 4)
#pragma unroll
            for (int k = 0; k < 2; ++k) {
                float cs = C8[4 * k], sn = S8n[4 * k];
                int i0 = b0 + k, i1 = i0 + 2;
                float arr = fr[i0], aii = fi[i0], brr = fr[i1], bii = fi[i1];
                fr[i0] = arr + brr; fi[i0] = aii + bii;
                float dr = arr - brr, di = aii - bii;
                fr[i1] = dr * cs - di * sn; fi[i1] = dr * sn + di * cs;
            }
#pragma unroll
        for (int b0 = 0; b0 < 16; b0 += 2) {
            float arr = fr[b0], aii = fi[b0], brr = fr[b0 + 1], bii = fi[b0 + 1];
            fr[b0] = arr + brr; fi[b0] = aii + bii;
            fr[b0 + 1] = arr - brr; fi[b0 + 1] = aii - bii;
        }
#pragma unroll
        for (int e = 0; e < 16; ++e) { Ar[pb + e] = fr[e]; Ai[pb + e] = fi[e]; }
        __syncthreads();
    }
}

// ---------------- inverse FFT: register head + 3 radix-8 LDS passes --------------
__device__ __forceinline__ void fft_inv(float* Ar, float* Ai, int t)
{
    {
        int pb = IDX(16 * t);
        float fr[16], fi[16];
#pragma unroll
        for (int e = 0; e < 16; ++e) { fr[e] = Ar[pb + e]; fi[e] = Ai[pb + e]; }
#pragma unroll
        for (int b0 = 0; b0 < 16; b0 += 2) {
            float arr = fr[b0], aii = fi[b0], brr = fr[b0 + 1], bii = fi[b0 + 1];
            fr[b0] = arr + brr; fi[b0] = aii + bii;
            fr[b0 + 1] = arr - brr; fi[b0 + 1] = aii - bii;
        }
#pragma unroll
        for (int b0 = 0; b0 < 16; b0 += 4)
#pragma unroll
            for (int k = 0; k < 2; ++k) {
                float cs = C8[4 * k], sn = S8p[4 * k];
                int i0 = b0 + k, i1 = i0 + 2;
                float arr = fr[i0], aii = fi[i0], brr = fr[i1], bii = fi[i1];
                float tr = brr * cs - bii * sn, ti = brr * sn + bii * cs;
                fr[i0] = arr + tr; fi[i0] = aii + ti;
                fr[i1] = arr - tr; fi[i1] = aii - ti;
            }
#pragma unroll
        for (int b0 = 0; b0 < 16; b0 += 8)
#pragma unroll
            for (int k = 0; k < 4; ++k) {
                float cs = C8[2 * k], sn = S8p[2 * k];
                int i0 = b0 + k, i1 = i0 + 4;
                float arr = fr[i0], aii = fi[i0], brr = fr[i1], bii = fi[i1];
                float tr = brr * cs - bii * sn, ti = brr * sn + bii * cs;
                fr[i0] = arr + tr; fi[i0] = aii + ti;
                fr[i1] = arr - tr; fi[i1] = aii - ti;
            }
#pragma unroll
        for (int k = 0; k < 8; ++k) {
            float cs = C8[k], sn = S8p[k];
            float arr = fr[k], aii = fi[k], brr = fr[k + 8], bii = fi[k + 8];
            float tr = brr * cs - bii * sn, ti = brr * sn + bii * cs;
            fr[k] = arr + tr; fi[k] = aii + ti;
            fr[k + 8] = arr - tr; fi[k + 8] = aii - ti;
        }
#pragma unroll
        for (int e = 0; e < 16; ++e) { Ar[pb + e] = fr[e]; Ai[pb + e] = fi[e]; }
        __syncthreads();
    }
    inv8<16>(Ar, Ai, t);   __syncthreads();   // 16,32,64
    inv8<128>(Ar, Ai, t);  __syncthreads();   // 128,256,512
    inv8<1024>(Ar, Ai, t); __syncthreads();   // 1024,2048,4096
}

// ---------------- kf: K_f[d] = rfft(k_d, 16384), fp16-packed into d_out rows ----
__global__ __launch_bounds__(512, 4) void kf_kernel(float* outk)
{
    __shared__ float Are[LDS_SZ], Aim[LDS_SZ];
    int t = threadIdx.x, d = blockIdx.x;
    const float* kp = outk + (size_t)d * SEQ;
    for (int n = t; n < 4096; n += 512) {
        float2 v = ((const float2*)kp)[n];
        Are[IDX(n)] = v.x; Aim[IDX(n)] = v.y;
    }
    for (int n = 4096 + t; n < M; n += 512) { Are[IDX(n)] = 0.f; Aim[IDX(n)] = 0.f; }
    __syncthreads();
    fft_fwd(Are, Aim, t);

    __half2* P0 = (__half2*)(outk + (size_t)d * SEQ);
    __half2* P1 = (__half2*)(outk + (size_t)(D_MODEL + d) * SEQ);
    float cs, sn;
    __sincosf(-PI_F * (float)t * (1.0f / 8192.0f), &sn, &cs);
    const float cRo = 0.9807852804f, sRo = -0.1950903220f;   // exp(-i*pi/16)
    for (int j = t; j <= 4096; j += 512) {
        int jm = (M - j) & (M - 1);
        int p0 = rev13(j), p1 = rev13(jm);
        float z1r = Are[IDX(p0)], z1i = Aim[IDX(p0)];
        float z2r = Are[IDX(p1)], z2i = Aim[IDX(p1)];
        float Ar_ = 0.5f * (z1r + z2r), Ai_ = 0.5f * (z1i - z2i);
        float Br_ = 0.5f * (z1i + z2i), Bi_ = 0.5f * (z2r - z1r);
        float wbr = cs * Br_ - sn * Bi_, wbi = cs * Bi_ + sn * Br_;
        float K1r = Ar_ + wbr, K1i = Ai_ + wbi;
        float K2r = Ar_ - wbr, K2i = -(Ai_ - wbi);
        if (j == 0) {
            __half2 v = __floats2half2_rn(K1r, K2r);
            P0[0] = v; P1[0] = v;
        } else {
            __half2 v1 = __floats2half2_rn(K1r, K1i);
            P0[j] = v1; P1[j] = v1;
            if (j != 4096) {
                __half2 v2 = __floats2half2_rn(K2r, K2i);
                P0[M - j] = v2; P1[M - j] = v2;
            }
        }
        float cn = cs * cRo - sn * sRo; sn = sn * cRo + cs * sRo; cs = cn;
    }
}

// ---------------- conv: block (d,b): y = irfft(rfft(x)*K)[:8192] + x*bias -------
__global__ __launch_bounds__(512, 4) void conv_kernel(
    const float* __restrict__ x, const float* __restrict__ bias,
    float* outk)
{
    __shared__ float Are[LDS_SZ], Aim[LDS_SZ];
    int t = threadIdx.x, d = blockIdx.x, b = blockIdx.y;
    const float* xp = x + ((size_t)(b * D_MODEL + d)) * SEQ;

    float2 xv[8];
#pragma unroll
    for (int idx = 0; idx < 8; ++idx) {
        int n = t + (idx << 9);
        xv[idx] = ((const float2*)xp)[n];
        Are[IDX(n)] = xv[idx].x; Aim[IDX(n)] = xv[idx].y;
    }
    for (int n = 4096 + t; n < M; n += 512) { Are[IDX(n)] = 0.f; Aim[IDX(n)] = 0.f; }
    __syncthreads();
    fft_fwd(Are, Aim, t);

    const __half2* P = (const __half2*)(outk + (size_t)(b * D_MODEL + d) * SEQ);
    float cs, sn;
    __sincosf(-PI_F * (float)t * (1.0f / 8192.0f), &sn, &cs);
    const float cRo = 0.9807852804f, sRo = -0.1950903220f;   // exp(-i*pi/16)
    for (int j = t; j <= 4096; j += 512) {
        int jm = (M - j) & (M - 1);
        int p0 = rev13(j), p1 = rev13(jm);
        int q0 = IDX(p0), q1 = IDX(p1);
        float z1r = Are[q0], z1i = Aim[q0];
        float z2r = Are[q1], z2i = Aim[q1];
        float Ar_ = 0.5f * (z1r + z2r), Ai_ = 0.5f * (z1i - z2i);
        float Br_ = 0.5f * (z1i + z2i), Bi_ = 0.5f * (z2r - z1r);
        float wbr = cs * Br_ - sn * Bi_, wbi = cs * Bi_ + sn * Br_;
        float U1r = Ar_ + wbr, U1i = Ai_ + wbi;
        float U2r = Ar_ - wbr, U2i = -(Ai_ - wbi);
        float K1r, K1i, K2r, K2i;
        if (j == 0) {
            __half2 v = P[0];
            K1r = __low2float(v);  K1i = 0.f;
            K2r = __high2float(v); K2i = 0.f;
        } else {
            __half2 v1 = P[j];
            __half2 v2 = P[M - j];
            K1r = __low2float(v1); K1i = __high2float(v1);
            K2r = __low2float(v2); K2i = __high2float(v2);
        }
        float P1r = U1r * K1r - U1i * K1i, P1i = U1r * K1i + U1i * K1r;
        float P2r = U2r * K2r - U2i * K2i, P2i = U2r * K2i + U2i * K2r;
        float Er = 0.5f * (P1r + P2r), Ei = 0.5f * (P1i - P2i);
        float Or = 0.5f * (P1r - P2r), Oi = 0.5f * (P1i + P2i);
        float G = cs * Oi - sn * Or;
        float H = cs * Or + sn * Oi;
        Are[q0] = Er - G; Aim[q0] = Ei + H;
        if (j != 0) { Are[q1] = Er + G; Aim[q1] = -Ei + H; }
        float cn = cs * cRo - sn * sRo; sn = sn * cRo + cs * sRo; cs = cn;
    }
    __syncthreads();
    fft_inv(Are, Aim, t);

    const float invM = 1.0f / 8192.0f;
    float bd = bias[d];
    float* op = outk + ((size_t)(b * D_MODEL + d)) * SEQ;
#pragma unroll
    for (int idx = 0; idx < 8; ++idx) {
        int n = t + (idx << 9);
        float2 ov;
        ov.x = fmaf(Are[IDX(n)], invM, xv[idx].x * bd);
        ov.y = fmaf(Aim[IDX(n)], invM, xv[idx].y * bd);
        ((float2*)op)[n] = ov;
    }
}

extern "C" void kernel_launch(void* const* d_in, const int* in_sizes, int n_in,
                              void* d_out, int out_size, void* d_ws, size_t ws_size,
                              hipStream_t stream)
{
    (void)in_sizes; (void)n_in; (void)out_size; (void)d_ws; (void)ws_size;
    const float* x      = (const float*)d_in[0];
    // d_in[1] = L (always 8192, hardcoded)
    const float* z      = (const float*)d_in[2];
    const float* tvec   = (const float*)d_in[3];
    const float* freq   = (const float*)d_in[4];
    const float* W1     = (const float*)d_in[5];
    const float* b1     = (const float*)d_in[6];
    const float* W2     = (const float*)d_in[7];
    const float* b2     = (const float*)d_in[8];
    const float* W3     = (const float*)d_in[9];
    const float* b3     = (const float*)d_in[10];
    const float* Wout   = (const float*)d_in[11];
    const float* deltas = (const float*)d_in[12];
    const float* bias   = (const float*)d_in[13];
    float* out = (float*)d_out;

    // staging inside d_out (12,582,912 floats):
    //   h3 -> last 64 rows of b=1 half (dead after filt_kernel)
    //   k  -> rows (0,d)   (consumed by kf block d, overwritten with packed K)
    //   K  -> rows (0,d) and (1,d) fp16-packed (consumed then overwritten by conv (d,b))
    float* h3 = out + ((size_t)(2 * D_MODEL - 64) * SEQ);
    float* k  = out;

    hipLaunchKernelGGL(mlp_kernel, dim3(SEQ / 64), dim3(256), 0, stream,
                       z, freq, W1, b1, W2, b2, W3, b3, h3);
    hipLaunchKernelGGL(filt_kernel, dim3(SEQ / 64, D_MODEL / 64), dim3(256), 0, stream,
                       h3, Wout, tvec, deltas, k);
    hipLaunchKernelGGL(kf_kernel, dim3(D_MODEL), dim3(512), 0, stream, out);
    hipLaunchKernelGGL(conv_kernel, dim3(D_MODEL, BATCH), dim3(512), 0, stream,
                       x, bias, out);
}

// Round 6
// 245.189 us; speedup vs baseline: 2.1872x; 1.0697x over previous
//
#include <hip/hip_runtime.h>
#include <hip/hip_fp16.h>
#include <math.h>

#define D_MODEL 768
#define EMB 33
#define ORDER 64
#define SEQ 8192
#define BATCH 2
#define M 8192      // half-size complex FFT length (N = 16384 real)

#define PI_F 3.14159265358979323846f

// padded LDS index: +1 per 16, +1 per 128 (odd shifts kill stride-16/128 bank patterns)
#define IDX(a) ((a) + ((a) >> 4) + ((a) >> 7))
#define LDS_SZ 8768

__device__ __forceinline__ int rev13(int x) { return (int)(__brev((unsigned)x) >> 19); }

// twiddle constants for register tail/head (angle pi*k/8)
__device__ __constant__ float C8[8] = {
    1.f, 0.9238795325f, 0.7071067812f, 0.3826834324f,
    0.f, -0.3826834324f, -0.7071067812f, -0.9238795325f };
__device__ __constant__ float S8n[8] = {   // -sin(pi k/8)  (forward DIF)
    0.f, -0.3826834324f, -0.7071067812f, -0.9238795325f,
    -1.f, -0.9238795325f, -0.7071067812f, -0.3826834324f };
__device__ __constant__ float S8p[8] = {   // +sin(pi k/8)  (inverse DIT)
    0.f, 0.3826834324f, 0.7071067812f, 0.9238795325f,
    1.f, 0.9238795325f, 0.7071067812f, 0.3826834324f };

// ---------------- MLP: h3T[o][l] = sin-MLP(z[l])[o], register-tiled ----------
// Block = 64 l-values. Thread tile = 4l x 4o. All LDS reads are b128.
__global__ __launch_bounds__(256) void mlp_kernel(
    const float* __restrict__ z, const float* __restrict__ freq,
    const float* __restrict__ W1, const float* __restrict__ b1,
    const float* __restrict__ W2, const float* __restrict__ b2,
    const float* __restrict__ W3, const float* __restrict__ b3,
    float* __restrict__ h3T)
{
    __shared__ float zt[33 * 72];    // zt[e][l], rows of 72 (288B, 16B-aligned)
    __shared__ float h1[64 * 72];    // h[o][l]
    __shared__ float h2[64 * 72];
    __shared__ float Wb[64 * 68];    // W[e][o], rows of 68 (272B, 16B-aligned)
    __shared__ float sfr[64], sb[64];
    int t = threadIdx.x;
    int l0 = blockIdx.x * 64;

    for (int i = t; i < 64 * 33; i += 256) {
        int l = i / 33, e = i - l * 33;
        zt[e * 72 + l] = z[(size_t)(l0 + l) * 33 + e];
    }
    for (int i = t; i < 64 * 33; i += 256) {
        int o = i / 33, e = i - o * 33;
        Wb[e * 68 + o] = W1[i];
    }
    if (t < 64) { sfr[t] = freq[t]; sb[t] = b1[t]; }
    __syncthreads();

    int lx = t & 15, oy = t >> 4;           // 16 lx * 4l = 64 l; 16 oy * 4o = 64 o
    float fr4[4], bi4[4], acc[4][4];
#pragma unroll
    for (int i = 0; i < 4; ++i) { fr4[i] = sfr[4 * oy + i]; bi4[i] = sb[4 * oy + i]; }
#pragma unroll
    for (int c = 0; c < 4; ++c)
#pragma unroll
        for (int i = 0; i < 4; ++i) acc[c][i] = bi4[i];
    for (int e = 0; e < 33; ++e) {
        float4 hv = *(const float4*)&zt[e * 72 + 4 * lx];
        float4 wv = *(const float4*)&Wb[e * 68 + 4 * oy];
        float h[4] = {hv.x, hv.y, hv.z, hv.w}, w[4] = {wv.x, wv.y, wv.z, wv.w};
#pragma unroll
        for (int c = 0; c < 4; ++c)
#pragma unroll
            for (int i = 0; i < 4; ++i) acc[c][i] = fmaf(h[c], w[i], acc[c][i]);
    }
#pragma unroll
    for (int i = 0; i < 4; ++i) {
        float4 v = make_float4(__sinf(fr4[i] * acc[0][i]), __sinf(fr4[i] * acc[1][i]),
                               __sinf(fr4[i] * acc[2][i]), __sinf(fr4[i] * acc[3][i]));
        *(float4*)&h1[(4 * oy + i) * 72 + 4 * lx] = v;
    }
    __syncthreads();

    for (int i = t; i < 4096; i += 256) {    // W2[o][q] -> Wb[q][o]
        int o = i >> 6, q = i & 63;
        Wb[q * 68 + o] = W2[i];
    }
    if (t < 64) sb[t] = b2[t];
    __syncthreads();
#pragma unroll
    for (int i = 0; i < 4; ++i) bi4[i] = sb[4 * oy + i];
#pragma unroll
    for (int c = 0; c < 4; ++c)
#pragma unroll
        for (int i = 0; i < 4; ++i) acc[c][i] = bi4[i];
    for (int q = 0; q < 64; ++q) {
        float4 hv = *(const float4*)&h1[q * 72 + 4 * lx];
        float4 wv = *(const float4*)&Wb[q * 68 + 4 * oy];
        float h[4] = {hv.x, hv.y, hv.z, hv.w}, w[4] = {wv.x, wv.y, wv.z, wv.w};
#pragma unroll
        for (int c = 0; c < 4; ++c)
#pragma unroll
            for (int i = 0; i < 4; ++i) acc[c][i] = fmaf(h[c], w[i], acc[c][i]);
    }
#pragma unroll
    for (int i = 0; i < 4; ++i) {
        float4 v = make_float4(__sinf(fr4[i] * acc[0][i]), __sinf(fr4[i] * acc[1][i]),
                               __sinf(fr4[i] * acc[2][i]), __sinf(fr4[i] * acc[3][i]));
        *(float4*)&h2[(4 * oy + i) * 72 + 4 * lx] = v;
    }
    __syncthreads();

    for (int i = t; i < 4096; i += 256) {    // W3[o][q] -> Wb[q][o]
        int o = i >> 6, q = i & 63;
        Wb[q * 68 + o] = W3[i];
    }
    if (t < 64) sb[t] = b3[t];
    __syncthreads();
#pragma unroll
    for (int i = 0; i < 4; ++i) bi4[i] = sb[4 * oy + i];
#pragma unroll
    for (int c = 0; c < 4; ++c)
#pragma unroll
        for (int i = 0; i < 4; ++i) acc[c][i] = bi4[i];
    for (int q = 0; q < 64; ++q) {
        float4 hv = *(const float4*)&h2[q * 72 + 4 * lx];
        float4 wv = *(const float4*)&Wb[q * 68 + 4 * oy];
        float h[4] = {hv.x, hv.y, hv.z, hv.w}, w[4] = {wv.x, wv.y, wv.z, wv.w};
#pragma unroll
        for (int c = 0; c < 4; ++c)
#pragma unroll
            for (int i = 0; i < 4; ++i) acc[c][i] = fmaf(h[c], w[i], acc[c][i]);
    }
#pragma unroll
    for (int i = 0; i < 4; ++i) {
        float4 v = make_float4(__sinf(fr4[i] * acc[0][i]), __sinf(fr4[i] * acc[1][i]),
                               __sinf(fr4[i] * acc[2][i]), __sinf(fr4[i] * acc[3][i]));
        *(float4*)&h3T[(size_t)(4 * oy + i) * SEQ + l0 + 4 * lx] = v;
    }
}

// ------- filter: k[d][l] = (h3[l]·Wout[d]) * exp(-t[l]*|delta[d]|), tiled -------
// Block = 128 l x 64 d. Thread tile = 4l x 8d. Grid 64x12 = 768 = 3 blocks/CU.
__global__ __launch_bounds__(256) void filt_kernel(
    const float* __restrict__ h3T, const float* __restrict__ Wout,
    const float* __restrict__ tvec, const float* __restrict__ deltas,
    float* __restrict__ kout)
{
    __shared__ float ht[64 * 132];   // ht[kk][l], rows 132 (528B, 16B-aligned)
    __shared__ float wt[64 * 68];    // wt[kk][dd], rows 68
    int t = threadIdx.x;
    int l0 = blockIdx.x * 128, d0 = blockIdx.y * 64;

    for (int i = t; i < 64 * 128; i += 256) {
        int o = i >> 7, l = i & 127;
        ht[o * 132 + l] = h3T[(size_t)o * SEQ + l0 + l];
    }
    for (int i = t; i < 4096; i += 256) {    // Wout[d][kk] -> wt[kk][dd]
        int dd = i >> 6, kk = i & 63;
        wt[kk * 68 + dd] = Wout[(size_t)(d0 + dd) * 64 + kk];
    }
    __syncthreads();

    int lx = t & 31, dy = t >> 5;            // 32 lx * 4l = 128; 8 dy * 8d = 64
    float acc[4][8];
#pragma unroll
    for (int c = 0; c < 4; ++c)
#pragma unroll
        for (int i = 0; i < 8; ++i) acc[c][i] = 0.f;
    for (int kk = 0; kk < 64; ++kk) {
        float4 hv = *(const float4*)&ht[kk * 132 + 4 * lx];
        float4 w0 = *(const float4*)&wt[kk * 68 + 8 * dy];
        float4 w1 = *(const float4*)&wt[kk * 68 + 8 * dy + 4];
        float h[4] = {hv.x, hv.y, hv.z, hv.w};
        float w[8] = {w0.x, w0.y, w0.z, w0.w, w1.x, w1.y, w1.z, w1.w};
#pragma unroll
        for (int c = 0; c < 4; ++c)
#pragma unroll
            for (int i = 0; i < 8; ++i) acc[c][i] = fmaf(h[c], w[i], acc[c][i]);
    }

    float4 tl4 = *(const float4*)&tvec[l0 + 4 * lx];
    float tl[4] = {tl4.x, tl4.y, tl4.z, tl4.w};
    float del[8];
#pragma unroll
    for (int i = 0; i < 8; ++i) del[i] = fabsf(deltas[d0 + 8 * dy + i]);
#pragma unroll
    for (int i = 0; i < 8; ++i) {
        int d = d0 + 8 * dy + i;
        float4 v = make_float4(acc[0][i] * __expf(-tl[0] * del[i]),
                               acc[1][i] * __expf(-tl[1] * del[i]),
                               acc[2][i] * __expf(-tl[2] * del[i]),
                               acc[3][i] * __expf(-tl[3] * del[i]));
        *(float4*)&kout[(size_t)d * SEQ + l0 + 4 * lx] = v;
    }
}

// ---------------- radix-8 fused forward pass: stages (H, H/2, H/4) ---------------
template<int H>
__device__ __forceinline__ void fwd8(float* Ar, float* Ai, int t)
{
    constexpr int H4 = H / 4;
    int j0 = t & (H4 - 1);
    float c1, s1;
    __sincosf((-PI_F / (float)H) * (float)j0, &s1, &c1);
#pragma unroll
    for (int gg = 0; gg < 2; ++gg) {
        int g = t + (gg << 9);
        int j = g & (H4 - 1);
        int i = ((g & ~(H4 - 1)) << 3) | j;
        float c1g = c1, s1g = s1;
        if (H4 > 512 && gg == 1) {       // only H=4096: j differs by 512 -> rotate T1
            const float cR = 0.9238795325f, sR = -0.3826834324f;  // exp(-i*pi/8)
            c1g = c1 * cR - s1 * sR;
            s1g = s1 * cR + c1 * sR;
        }
        float c2 = c1g * c1g - s1g * s1g, s2 = 2.f * c1g * s1g;   // T1^2
        float c3 = c2 * c2 - s2 * s2,     s3 = 2.f * c2 * s2;     // T1^4
        float xr[8], xi[8];
        int ad[8];
#pragma unroll
        for (int m = 0; m < 8; ++m) { ad[m] = IDX(i + m * H4); xr[m] = Ar[ad[m]]; xi[m] = Ai[ad[m]]; }
        const float r = 0.70710678118f;
        float twc[4], tws[4];                                      // T1 * W8^m
        twc[0] = c1g;             tws[0] = s1g;
        twc[1] = r * (c1g + s1g); tws[1] = r * (s1g - c1g);
        twc[2] = s1g;             tws[2] = -c1g;
        twc[3] = r * (s1g - c1g); tws[3] = -r * (c1g + s1g);
#pragma unroll
        for (int m = 0; m < 4; ++m) {                              // stage half=H
            float ur = xr[m] + xr[m + 4], ui = xi[m] + xi[m + 4];
            float dr = xr[m] - xr[m + 4], di = xi[m] - xi[m + 4];
            xr[m] = ur; xi[m] = ui;
            xr[m + 4] = dr * twc[m] - di * tws[m];
            xi[m + 4] = dr * tws[m] + di * twc[m];
        }
#pragma unroll
        for (int base = 0; base < 8; base += 4)                    // stage half=H/2
#pragma unroll
            for (int mm = 0; mm < 2; ++mm) {
                int a = base + mm, b = a + 2;
                float ur = xr[a] + xr[b], ui = xi[a] + xi[b];
                float dr = xr[a] - xr[b], di = xi[a] - xi[b];
                xr[a] = ur; xi[a] = ui;
                if (mm == 0) { xr[b] = dr * c2 - di * s2; xi[b] = dr * s2 + di * c2; }
                else         { xr[b] = dr * s2 + di * c2; xi[b] = di * s2 - dr * c2; }  // *T2*(-i)
            }
#pragma unroll
        for (int m = 0; m < 8; m += 2) {                           // stage half=H/4
            float ur = xr[m] + xr[m + 1], ui = xi[m] + xi[m + 1];
            float dr = xr[m] - xr[m + 1], di = xi[m] - xi[m + 1];
            xr[m] = ur; xi[m] = ui;
            xr[m + 1] = dr * c3 - di * s3; xi[m + 1] = dr * s3 + di * c3;
        }
#pragma unroll
        for (int m = 0; m < 8; ++m) { Ar[ad[m]] = xr[m]; Ai[ad[m]] = xi[m]; }
    }
}

// ---------------- radix-8 fused inverse pass: stages (H, 2H, 4H) -----------------
template<int H>
__device__ __forceinline__ void inv8(float* Ar, float* Ai, int t)
{
    int j0 = t & (H - 1);
    float ct, st;
    __sincosf((PI_F / (float)(4 * H)) * (float)j0, &st, &ct);      // T = exp(i pi j/(4H))
#pragma unroll
    for (int gg = 0; gg < 2; ++gg) {
        int g = t + (gg << 9);
        int j = g & (H - 1);
        int i = ((g & ~(H - 1)) << 3) | j;
        float c = ct, s = st;
        if (H > 512 && gg == 1) {        // only H=1024: j differs by 512 -> rotate T
            const float cR = 0.9238795325f, sR = 0.3826834324f;    // exp(+i*pi/8)
            c = ct * cR - st * sR;
            s = st * cR + ct * sR;
        }
        float c2 = c * c - s * s, s2 = 2.f * c * s;                // T^2
        float c4 = c2 * c2 - s2 * s2, s4 = 2.f * c2 * s2;          // T^4
        float xr[8], xi[8]; int ad[8];
#pragma unroll
        for (int m = 0; m < 8; ++m) { ad[m] = IDX(i + m * H); xr[m] = Ar[ad[m]]; xi[m] = Ai[ad[m]]; }
#pragma unroll
        for (int m = 0; m < 8; m += 2) {
            float tr = xr[m + 1] * c4 - xi[m + 1] * s4;
            float ti = xr[m + 1] * s4 + xi[m + 1] * c4;
            xr[m + 1] = xr[m] - tr; xi[m + 1] = xi[m] - ti;
            xr[m]     = xr[m] + tr; xi[m]     = xi[m] + ti;
        }
#pragma unroll
        for (int base = 0; base < 8; base += 4)
#pragma unroll
            for (int mm = 0; mm < 2; ++mm) {
                int a = base + mm, b = a + 2;
                float tr, ti;
                if (mm == 0) { tr = xr[b] * c2 - xi[b] * s2; ti = xr[b] * s2 + xi[b] * c2; }
                else         { tr = -(xr[b] * s2 + xi[b] * c2); ti = xr[b] * c2 - xi[b] * s2; }
                xr[b] = xr[a] - tr; xi[b] = xi[a] - ti;
                xr[a] = xr[a] + tr; xi[a] = xi[a] + ti;
            }
        const float r = 0.70710678118f;
        float t3c[4], t3s[4];
        t3c[0] = c;           t3s[0] = s;
        t3c[1] = r * (c - s); t3s[1] = r * (c + s);
        t3c[2] = -s;          t3s[2] = c;
        t3c[3] = -r * (c + s); t3s[3] = r * (c - s);
#pragma unroll
        for (int m = 0; m < 4; ++m) {
            float tr = xr[m + 4] * t3c[m] - xi[m + 4] * t3s[m];
            float ti = xr[m + 4] * t3s[m] + xi[m + 4] * t3c[m];
            xr[m + 4] = xr[m] - tr; xi[m + 4] = xi[m] - ti;
            xr[m]     = xr[m] + tr; xi[m]     = xi[m] + ti;
        }
#pragma unroll
        for (int m = 0; m < 8; ++m) { Ar[ad[m]] = xr[m]; Ai[ad[m]] = xi[m]; }
    }
}

// ---------------- forward FFT: 3 radix-8 LDS passes + register tail --------------
__device__ __forceinline__ void fft_fwd(float* Ar, float* Ai, int t)
{
    fwd8<4096>(Ar, Ai, t); __syncthreads();
    fwd8<512>(Ar, Ai, t);  __syncthreads();
    fwd8<64>(Ar, Ai, t);   __syncthreads();
    {
        int pb = IDX(16 * t);
        float fr[16], fi[16];
#pragma unroll
        for (int e = 0; e < 16; ++e) { fr[e] = Ar[pb + e]; fi[e] = Ai[pb + e]; }
#pragma unroll
        for (int k = 0; k < 8; ++k) {
            float cs = C8[k], sn = S8n[k];
            float arr = fr[k], aii = fi[k], brr = fr[k + 8], bii = fi[k + 8];
            fr[k] = arr + brr; fi[k] = aii + bii;
            float dr = arr - brr, di = aii - bii;
            fr[k + 8] = dr * cs - di * sn; fi[k + 8] = dr * sn + di * cs;
        }
#pragma unroll
        for (int b0 = 0; b0 < 16; b0 += 8)
#pragma unroll
            for (int k = 0; k < 4; ++k) {
                float cs = C8[2 * k], sn = S8n[2 * k];
                int i0 = b0 + k, i1 = i0 + 4;
                float arr = fr[i0], aii = fi[i0], brr = fr[i1], bii = fi[i1];
                fr[i0] = arr + brr; fi[i0] = aii + bii;
                float dr = arr - brr, di = aii - bii;
                fr[i1] = dr * cs - di * sn; fi[i1] = dr * sn + di * cs;
            }
#pragma unroll
        for (int b0 = 0; b0 < 16; b0 += 4)
#pragma unroll
            for (int k = 0; k < 2; ++k) {
                float cs = C8[4 * k], sn = S8n[4 * k];
                int i0 = b0 + k, i1 = i0 + 2;
                float arr = fr[i0], aii = fi[i0], brr = fr[i1], bii = fi[i1];
                fr[i0] = arr + brr; fi[i0] = aii + bii;
                float dr = arr - brr, di = aii - bii;
                fr[i1] = dr * cs - di * sn; fi[i1] = dr * sn + di * cs;
            }
#pragma unroll
        for (int b0 = 0; b0 < 16; b0 += 2) {
            float arr = fr[b0], aii = fi[b0], brr = fr[b0 + 1], bii = fi[b0 + 1];
            fr[b0] = arr + brr; fi[b0] = aii + bii;
            fr[b0 + 1] = arr - brr; fi[b0 + 1] = aii - bii;
        }
#pragma unroll
        for (int e = 0; e < 16; ++e) { Ar[pb + e] = fr[e]; Ai[pb + e] = fi[e]; }
        __syncthreads();
    }
}

// ---------------- inverse FFT: register head + 3 radix-8 LDS passes --------------
__device__ __forceinline__ void fft_inv(float* Ar, float* Ai, int t)
{
    {
        int pb = IDX(16 * t);
        float fr[16], fi[16];
#pragma unroll
        for (int e = 0; e < 16; ++e) { fr[e] = Ar[pb + e]; fi[e] = Ai[pb + e]; }
#pragma unroll
        for (int b0 = 0; b0 < 16; b0 += 2) {
            float arr = fr[b0], aii = fi[b0], brr = fr[b0 + 1], bii = fi[b0 + 1];
            fr[b0] = arr + brr; fi[b0] = aii + bii;
            fr[b0 + 1] = arr - brr; fi[b0 + 1] = aii - bii;
        }
#pragma unroll
        for (int b0 = 0; b0 < 16; b0 += 4)
#pragma unroll
            for (int k = 0; k < 2; ++k) {
                float cs = C8[4 * k], sn = S8p[4 * k];
                int i0 = b0 + k, i1 = i0 + 2;
                float arr = fr[i0], aii = fi[i0], brr = fr[i1], bii = fi[i1];
                float tr = brr * cs - bii * sn, ti = brr * sn + bii * cs;
                fr[i0] = arr + tr; fi[i0] = aii + ti;
                fr[i1] = arr - tr; fi[i1] = aii - ti;
            }
#pragma unroll
        for (int b0 = 0; b0 < 16; b0 += 8)
#pragma unroll
            for (int k = 0; k < 4; ++k) {
                float cs = C8[2 * k], sn = S8p[2 * k];
                int i0 = b0 + k, i1 = i0 + 4;
                float arr = fr[i0], aii = fi[i0], brr = fr[i1], bii = fi[i1];
                float tr = brr * cs - bii * sn, ti = brr * sn + bii * cs;
                fr[i0] = arr + tr; fi[i0] = aii + ti;
                fr[i1] = arr - tr; fi[i1] = aii - ti;
            }
#pragma unroll
        for (int k = 0; k < 8; ++k) {
            float cs = C8[k], sn = S8p[k];
            float arr = fr[k], aii = fi[k], brr = fr[k + 8], bii = fi[k + 8];
            float tr = brr * cs - bii * sn, ti = brr * sn + bii * cs;
            fr[k] = arr + tr; fi[k] = aii + ti;
            fr[k + 8] = arr - tr; fi[k + 8] = aii - ti;
        }
#pragma unroll
        for (int e = 0; e < 16; ++e) { Ar[pb + e] = fr[e]; Ai[pb + e] = fi[e]; }
        __syncthreads();
    }
    inv8<16>(Ar, Ai, t);   __syncthreads();
    inv8<128>(Ar, Ai, t);  __syncthreads();
    inv8<1024>(Ar, Ai, t); __syncthreads();
}

// ---------------- kf: K_f[d] = rfft(k_d, 16384), fp16-packed into d_out rows ----
__global__ __launch_bounds__(512, 4) void kf_kernel(float* outk)
{
    __shared__ float Are[LDS_SZ], Aim[LDS_SZ];
    int t = threadIdx.x, d = blockIdx.x;
    const float* kp = outk + (size_t)d * SEQ;
    for (int n = t; n < 4096; n += 512) {
        float2 v = ((const float2*)kp)[n];
        Are[IDX(n)] = v.x; Aim[IDX(n)] = v.y;
    }
    for (int n = 4096 + t; n < M; n += 512) { Are[IDX(n)] = 0.f; Aim[IDX(n)] = 0.f; }
    __syncthreads();
    fft_fwd(Are, Aim, t);

    __half2* P0 = (__half2*)(outk + (size_t)d * SEQ);
    __half2* P1 = (__half2*)(outk + (size_t)(D_MODEL + d) * SEQ);
    float cs, sn;
    __sincosf(-PI_F * (float)t * (1.0f / 8192.0f), &sn, &cs);
    const float cRo = 0.9807852804f, sRo = -0.1950903220f;   // exp(-i*pi/16)
    for (int j = t; j <= 4096; j += 512) {
        int jm = (M - j) & (M - 1);
        int p0 = rev13(j), p1 = rev13(jm);
        float z1r = Are[IDX(p0)], z1i = Aim[IDX(p0)];
        float z2r = Are[IDX(p1)], z2i = Aim[IDX(p1)];
        float Ar_ = 0.5f * (z1r + z2r), Ai_ = 0.5f * (z1i - z2i);
        float Br_ = 0.5f * (z1i + z2i), Bi_ = 0.5f * (z2r - z1r);
        float wbr = cs * Br_ - sn * Bi_, wbi = cs * Bi_ + sn * Br_;
        float K1r = Ar_ + wbr, K1i = Ai_ + wbi;
        float K2r = Ar_ - wbr, K2i = -(Ai_ - wbi);
        if (j == 0) {
            __half2 v = __floats2half2_rn(K1r, K2r);
            P0[0] = v; P1[0] = v;
        } else {
            __half2 v1 = __floats2half2_rn(K1r, K1i);
            P0[j] = v1; P1[j] = v1;
            if (j != 4096) {
                __half2 v2 = __floats2half2_rn(K2r, K2i);
                P0[M - j] = v2; P1[M - j] = v2;
            }
        }
        float cn = cs * cRo - sn * sRo; sn = sn * cRo + cs * sRo; cs = cn;
    }
}

// ---------------- conv: block (d,b): y = irfft(rfft(x)*K)[:8192] + x*bias -------
__global__ __launch_bounds__(512, 4) void conv_kernel(
    const float* __restrict__ x, const float* __restrict__ bias,
    float* outk)
{
    __shared__ float Are[LDS_SZ], Aim[LDS_SZ];
    int t = threadIdx.x, d = blockIdx.x, b = blockIdx.y;
    const float* xp = x + ((size_t)(b * D_MODEL + d)) * SEQ;

    float2 xv[8];
#pragma unroll
    for (int idx = 0; idx < 8; ++idx) {
        int n = t + (idx << 9);
        xv[idx] = ((const float2*)xp)[n];
        Are[IDX(n)] = xv[idx].x; Aim[IDX(n)] = xv[idx].y;
    }
    for (int n = 4096 + t; n < M; n += 512) { Are[IDX(n)] = 0.f; Aim[IDX(n)] = 0.f; }
    __syncthreads();
    fft_fwd(Are, Aim, t);

    const __half2* P = (const __half2*)(outk + (size_t)(b * D_MODEL + d) * SEQ);
    float cs, sn;
    __sincosf(-PI_F * (float)t * (1.0f / 8192.0f), &sn, &cs);
    const float cRo = 0.9807852804f, sRo = -0.1950903220f;   // exp(-i*pi/16)
    for (int j = t; j <= 4096; j += 512) {
        int jm = (M - j) & (M - 1);
        int p0 = rev13(j), p1 = rev13(jm);
        int q0 = IDX(p0), q1 = IDX(p1);
        float z1r = Are[q0], z1i = Aim[q0];
        float z2r = Are[q1], z2i = Aim[q1];
        float Ar_ = 0.5f * (z1r + z2r), Ai_ = 0.5f * (z1i - z2i);
        float Br_ = 0.5f * (z1i + z2i), Bi_ = 0.5f * (z2r - z1r);
        float wbr = cs * Br_ - sn * Bi_, wbi = cs * Bi_ + sn * Br_;
        float U1r = Ar_ + wbr, U1i = Ai_ + wbi;
        float U2r = Ar_ - wbr, U2i = -(Ai_ - wbi);
        float K1r, K1i, K2r, K2i;
        if (j == 0) {
            __half2 v = P[0];
            K1r = __low2float(v);  K1i = 0.f;
            K2r = __high2float(v); K2i = 0.f;
        } else {
            __half2 v1 = P[j];
            __half2 v2 = P[M - j];
            K1r = __low2float(v1); K1i = __high2float(v1);
            K2r = __low2float(v2); K2i = __high2float(v2);
        }
        float P1r = U1r * K1r - U1i * K1i, P1i = U1r * K1i + U1i * K1r;
        float P2r = U2r * K2r - U2i * K2i, P2i = U2r * K2i + U2i * K2r;
        float Er = 0.5f * (P1r + P2r), Ei = 0.5f * (P1i - P2i);
        float Or = 0.5f * (P1r - P2r), Oi = 0.5f * (P1i + P2i);
        float G = cs * Oi - sn * Or;
        float H = cs * Or + sn * Oi;
        Are[q0] = Er - G; Aim[q0] = Ei + H;
        if (j != 0) { Are[q1] = Er + G; Aim[q1] = -Ei + H; }
        float cn = cs * cRo - sn * sRo; sn = sn * cRo + cs * sRo; cs = cn;
    }
    __syncthreads();
    fft_inv(Are, Aim, t);

    const float invM = 1.0f / 8192.0f;
    float bd = bias[d];
    float* op = outk + ((size_t)(b * D_MODEL + d)) * SEQ;
#pragma unroll
    for (int idx = 0; idx < 8; ++idx) {
        int n = t + (idx << 9);
        float2 ov;
        ov.x = fmaf(Are[IDX(n)], invM, xv[idx].x * bd);
        ov.y = fmaf(Aim[IDX(n)], invM, xv[idx].y * bd);
        ((float2*)op)[n] = ov;
    }
}

extern "C" void kernel_launch(void* const* d_in, const int* in_sizes, int n_in,
                              void* d_out, int out_size, void* d_ws, size_t ws_size,
                              hipStream_t stream)
{
    (void)in_sizes; (void)n_in; (void)out_size; (void)d_ws; (void)ws_size;
    const float* x      = (const float*)d_in[0];
    // d_in[1] = L (always 8192, hardcoded)
    const float* z      = (const float*)d_in[2];
    const float* tvec   = (const float*)d_in[3];
    const float* freq   = (const float*)d_in[4];
    const float* W1     = (const float*)d_in[5];
    const float* b1     = (const float*)d_in[6];
    const float* W2     = (const float*)d_in[7];
    const float* b2     = (const float*)d_in[8];
    const float* W3     = (const float*)d_in[9];
    const float* b3     = (const float*)d_in[10];
    const float* Wout   = (const float*)d_in[11];
    const float* deltas = (const float*)d_in[12];
    const float* bias   = (const float*)d_in[13];
    float* out = (float*)d_out;

    // staging inside d_out (12,582,912 floats):
    //   h3T (64 x 8192, transposed) -> last 64 rows of b=1 half (dead after filt)
    //   k  -> rows (0,d)   (consumed by kf block d, overwritten with packed K)
    //   K  -> rows (0,d) and (1,d) fp16-packed (consumed then overwritten by conv)
    float* h3T = out + ((size_t)(2 * D_MODEL - 64) * SEQ);
    float* k   = out;

    hipLaunchKernelGGL(mlp_kernel, dim3(SEQ / 64), dim3(256), 0, stream,
                       z, freq, W1, b1, W2, b2, W3, b3, h3T);
    hipLaunchKernelGGL(filt_kernel, dim3(SEQ / 128, D_MODEL / 64), dim3(256), 0, stream,
                       h3T, Wout, tvec, deltas, k);
    hipLaunchKernelGGL(kf_kernel, dim3(D_MODEL), dim3(512), 0, stream, out);
    hipLaunchKernelGGL(conv_kernel, dim3(D_MODEL, BATCH), dim3(512), 0, stream,
                       x, bias, out);
}